// Round 4
// baseline (477.265 us; speedup 1.0000x reference)
//
#include <hip/hip_runtime.h>
#include <hip/hip_bf16.h>

typedef short short8 __attribute__((ext_vector_type(8)));
typedef float floatx4 __attribute__((ext_vector_type(4)));

#define B_  256
#define T_  512
#define D_  64
#define L_  32
#define H_  128
#define PXS 516   // pre_x row stride in floats: 516%32=4 -> 2-way banks max

__device__ inline short f2bf(float f) {
    __hip_bfloat16 h = __float2bfloat16(f);
    union { __hip_bfloat16 h; short s; } u;
    u.h = h;
    return u.s;
}

__device__ inline float bf2f(short s) {
    union { float f; unsigned u; } u;
    u.u = ((unsigned)(unsigned short)s) << 16;
    return u.f;
}

__device__ inline float fast_sigmoid(float x) {
    return __builtin_amdgcn_rcpf(1.0f + __expf(-x));
}

__device__ inline float fast_tanh(float x) {
    float e = __expf(-2.0f * x);
    return 2.0f * __builtin_amdgcn_rcpf(1.0f + e) - 1.0f;
}

// One block per batch element; 512 threads = 8 waves; 1 block/CU (256 blocks).
// Wave w owns hidden cols [16w,16w+16) x 4 gate types -> i/f/g/o of a column
// land in one lane's accumulators -> in-register elementwise, c in registers.
// ONE barrier per step. Per-wave staggered duty work (window x@Wih MFMA with
// A-frags straight from global; deferred O=1 output dot) -> no burst steps,
// no staging barriers, no global stores inside the loop.
__global__ __launch_bounds__(512, 2) void tamlstm_kernel(
    const float* __restrict__ xd,    // [B,T,D]
    const float* __restrict__ xs,    // [B,L]
    const float* __restrict__ Wih,   // [4H,D]
    const float* __restrict__ Whh,   // [4H,H]
    const float* __restrict__ Wzh,   // [4H,L]
    const float* __restrict__ bias,  // [4H]
    const float* __restrict__ Wout,  // [1,H]
    const float* __restrict__ bout,  // [1]
    float* __restrict__ out)         // [B,T]
{
    const int b    = blockIdx.x;
    const int tid  = threadIdx.x;
    const int w    = tid >> 6;    // wave 0..7
    const int lane = tid & 63;
    const int l15  = lane & 15;
    const int q    = lane >> 4;   // quad 0..3

    __shared__ __align__(16) float pre_x[16][PXS];   // 33 KB: [t][col*4+e] packed
    __shared__ __align__(16) short h_ring[32][H_];   // 8 KB bf16 h history
    __shared__ float out_lds[T_];                    // 2 KB output buffer

    // zero h_ring (slot 0 = h_{-1} = 0)
    {
        int* hr = (int*)h_ring;  // 2048 ints
        #pragma unroll
        for (int i = 0; i < 4; ++i) hr[tid + 512 * i] = 0;
    }

    const int col = (w << 4) + l15;                 // hidden column 0..127

    // ---- B-fragments (bf16) in registers ----
    // B-frag element j = W[gate = col + 128e][k = 32s + 8q + j]
    short8 whh[4][4];  // [gate e][k-chunk s], K=128
    short8 wih[4][2];  // [e][s], K=64
    #pragma unroll
    for (int e = 0; e < 4; ++e) {
        const int g = col + (e << 7);
        const float* rh = Whh + g * H_;
        #pragma unroll
        for (int s = 0; s < 4; ++s) {
            const float* p = rh + s * 32 + q * 8;
            short8 v;
            #pragma unroll
            for (int j = 0; j < 8; ++j) v[j] = f2bf(p[j]);
            whh[e][s] = v;
        }
        const float* ri = Wih + g * D_;
        #pragma unroll
        for (int s = 0; s < 2; ++s) {
            const float* p = ri + s * 32 + q * 8;
            short8 v;
            #pragma unroll
            for (int j = 0; j < 8; ++j) v[j] = f2bf(p[j]);
            wih[e][s] = v;
        }
    }

    // ---- static part: bias + x_static @ Wzh^T ----
    float S[4];
    const float* xsb = xs + b * L_;
    #pragma unroll
    for (int e = 0; e < 4; ++e) {
        const int g = col + (e << 7);
        const float* wz = Wzh + g * L_;
        float a = bias[g];
        for (int l = 0; l < L_; ++l) a += xsb[l] * wz[l];
        S[e] = a;
    }
    const float wo0 = Wout[lane];
    const float wo1 = Wout[lane + 64];
    const float bo  = bout[0];

    const float* xb = xd + (size_t)b * T_ * D_;

    // ---- prologue: window-0 pre_x (each wave its own cols; M=16 timesteps) ----
    {
        const float* xr = xb + l15 * D_;            // timestep row l15
        float4 u00 = *(const float4*)(xr + q * 8);
        float4 u01 = *(const float4*)(xr + q * 8 + 4);
        float4 u10 = *(const float4*)(xr + 32 + q * 8);
        float4 u11 = *(const float4*)(xr + 32 + q * 8 + 4);
        short8 a0, a1;
        a0[0]=f2bf(u00.x); a0[1]=f2bf(u00.y); a0[2]=f2bf(u00.z); a0[3]=f2bf(u00.w);
        a0[4]=f2bf(u01.x); a0[5]=f2bf(u01.y); a0[6]=f2bf(u01.z); a0[7]=f2bf(u01.w);
        a1[0]=f2bf(u10.x); a1[1]=f2bf(u10.y); a1[2]=f2bf(u10.z); a1[3]=f2bf(u10.w);
        a1[4]=f2bf(u11.x); a1[5]=f2bf(u11.y); a1[6]=f2bf(u11.z); a1[7]=f2bf(u11.w);
        #pragma unroll
        for (int e = 0; e < 4; ++e) {
            floatx4 aw = __builtin_amdgcn_mfma_f32_16x16x32_bf16(a0, wih[e][0],
                             (floatx4){0.f, 0.f, 0.f, 0.f}, 0, 0, 0);
            aw = __builtin_amdgcn_mfma_f32_16x16x32_bf16(a1, wih[e][1], aw, 0, 0, 0);
            #pragma unroll
            for (int r = 0; r < 4; ++r)
                pre_x[q * 4 + r][(col << 2) + e] = aw[r];
        }
    }

    float c = 0.0f;
    floatx4 aw[4];             // next window's pre_x (this wave's cols)
    #pragma unroll
    for (int e = 0; e < 4; ++e) aw[e] = (floatx4){0.f, 0.f, 0.f, 0.f};

    __syncthreads();

    for (int t = 0; t < T_; ++t) {
        const int tw = t & 15;
        const int t0 = t & ~15;

        // ---------- per-wave staggered duty (wave-uniform branches) ----------
        if (tw == (w << 1) && (t0 + 16) < T_) {
            // window-(W+1) x@Wih MFMAs; A-frags straight from global (L3-hot).
            // Issued at step top -> ~700 cyc of cover before barrier drain.
            const float* xr = xb + (t0 + 16 + l15) * D_;
            float4 u00 = *(const float4*)(xr + q * 8);
            float4 u01 = *(const float4*)(xr + q * 8 + 4);
            float4 u10 = *(const float4*)(xr + 32 + q * 8);
            float4 u11 = *(const float4*)(xr + 32 + q * 8 + 4);
            short8 a0, a1;
            a0[0]=f2bf(u00.x); a0[1]=f2bf(u00.y); a0[2]=f2bf(u00.z); a0[3]=f2bf(u00.w);
            a0[4]=f2bf(u01.x); a0[5]=f2bf(u01.y); a0[6]=f2bf(u01.z); a0[7]=f2bf(u01.w);
            a1[0]=f2bf(u10.x); a1[1]=f2bf(u10.y); a1[2]=f2bf(u10.z); a1[3]=f2bf(u10.w);
            a1[4]=f2bf(u11.x); a1[5]=f2bf(u11.y); a1[6]=f2bf(u11.z); a1[7]=f2bf(u11.w);
            #pragma unroll
            for (int e = 0; e < 4; ++e) {
                aw[e] = __builtin_amdgcn_mfma_f32_16x16x32_bf16(a0, wih[e][0],
                            (floatx4){0.f, 0.f, 0.f, 0.f}, 0, 0, 0);
                aw[e] = __builtin_amdgcn_mfma_f32_16x16x32_bf16(a1, wih[e][1], aw[e], 0, 0, 0);
            }
        }
        if (tw == ((w << 1) | 1) && t0 > 0) {
            // deferred output dot for window W-1 (2 timesteps for this wave)
            const int tp = t0 - 16 + (w << 1);
            const int s0 = (tp + 1) & 31;
            const int s1 = (tp + 2) & 31;
            float p0 = bf2f(h_ring[s0][lane]) * wo0 + bf2f(h_ring[s0][lane + 64]) * wo1;
            float p1 = bf2f(h_ring[s1][lane]) * wo0 + bf2f(h_ring[s1][lane + 64]) * wo1;
            #pragma unroll
            for (int d = 32; d >= 1; d >>= 1) {
                p0 += __shfl_xor(p0, d);
                p1 += __shfl_xor(p1, d);
            }
            if (lane == 0) {
                out_lds[tp]     = p0 + bo;
                out_lds[tp + 1] = p1 + bo;
            }
        }

        // ---------- recurrent MFMA: g += h_{t-1} @ Whh^T ----------
        const short8* hp = (const short8*)h_ring[t & 31];
        short8 af0 = hp[q];
        short8 af1 = hp[4 + q];
        short8 af2 = hp[8 + q];
        short8 af3 = hp[12 + q];
        // pre_x packed read: one b128, quads broadcast
        floatx4 px = *(const floatx4*)&pre_x[tw][col << 2];

        floatx4 acc[4];
        #pragma unroll
        for (int e = 0; e < 4; ++e)
            acc[e] = __builtin_amdgcn_mfma_f32_16x16x32_bf16(af0, whh[e][0],
                         (floatx4){0.f, 0.f, 0.f, 0.f}, 0, 0, 0);
        #pragma unroll
        for (int e = 0; e < 4; ++e)
            acc[e] = __builtin_amdgcn_mfma_f32_16x16x32_bf16(af1, whh[e][1], acc[e], 0, 0, 0);
        #pragma unroll
        for (int e = 0; e < 4; ++e)
            acc[e] = __builtin_amdgcn_mfma_f32_16x16x32_bf16(af2, whh[e][2], acc[e], 0, 0, 0);
        #pragma unroll
        for (int e = 0; e < 4; ++e)
            acc[e] = __builtin_amdgcn_mfma_f32_16x16x32_bf16(af3, whh[e][3], acc[e], 0, 0, 0);

        // ---------- elementwise (quads duplicate) ----------
        const float gi = acc[0].x + px[0] + S[0];
        const float gf = acc[1].x + px[1] + S[1];
        const float gg = acc[2].x + px[2] + S[2];
        const float go = acc[3].x + px[3] + S[3];
        const float is = fast_sigmoid(gi);
        const float fs = fast_sigmoid(gf);
        const float os = fast_sigmoid(go);
        const float tg = fast_tanh(gg);
        c = fs * c + is * tg;
        const float h = os * fast_tanh(c);

        if (lane < 16) h_ring[(t + 1) & 31][col] = f2bf(h);

        // dump next window's pre_x AFTER this window's last read (wave-local)
        if (tw == 15 && (t0 + 16) < T_) {
            #pragma unroll
            for (int e = 0; e < 4; ++e)
                #pragma unroll
                for (int r = 0; r < 4; ++r)
                    pre_x[q * 4 + r][(col << 2) + e] = aw[e][r];
        }

        __syncthreads();
    }

    // ---- epilogue: outputs for t' = 496..511, then one coalesced store ----
    {
        const int tp = T_ - 16 + (w << 1);
        const int s0 = (tp + 1) & 31;
        const int s1 = (tp + 2) & 31;
        float p0 = bf2f(h_ring[s0][lane]) * wo0 + bf2f(h_ring[s0][lane + 64]) * wo1;
        float p1 = bf2f(h_ring[s1][lane]) * wo0 + bf2f(h_ring[s1][lane + 64]) * wo1;
        #pragma unroll
        for (int d = 32; d >= 1; d >>= 1) {
            p0 += __shfl_xor(p0, d);
            p1 += __shfl_xor(p1, d);
        }
        if (lane == 0) {
            out_lds[tp]     = p0 + bo;
            out_lds[tp + 1] = p1 + bo;
        }
    }
    __syncthreads();
    out[b * T_ + tid] = out_lds[tid];
}

extern "C" void kernel_launch(void* const* d_in, const int* in_sizes, int n_in,
                              void* d_out, int out_size, void* d_ws, size_t ws_size,
                              hipStream_t stream) {
    const float* xd   = (const float*)d_in[0];
    const float* xs   = (const float*)d_in[1];
    const float* Wih  = (const float*)d_in[2];
    const float* Whh  = (const float*)d_in[3];
    const float* Wzh  = (const float*)d_in[4];
    const float* bias = (const float*)d_in[5];
    const float* Wout = (const float*)d_in[6];
    const float* bout = (const float*)d_in[7];
    float* o = (float*)d_out;
    hipLaunchKernelGGL(tamlstm_kernel, dim3(B_), dim3(512), 0, stream,
                       xd, xs, Wih, Whh, Wzh, bias, Wout, bout, o);
}

// Round 5
// 376.150 us; speedup vs baseline: 1.2688x; 1.2688x over previous
//
#include <hip/hip_runtime.h>
#include <hip/hip_bf16.h>

typedef short short8 __attribute__((ext_vector_type(8)));
typedef float floatx4 __attribute__((ext_vector_type(4)));

#define B_  256
#define T_  512
#define D_  64
#define L_  32
#define H_  128
#define PXS 516   // pre_x row stride (floats); packed [t][col*4+e] -> 0 conflicts (R4-verified)

__device__ inline short f2bf(float f) {
    __hip_bfloat16 h = __float2bfloat16(f);
    union { __hip_bfloat16 h; short s; } u;
    u.h = h;
    return u.s;
}

__device__ inline float bf2f(short s) {
    union { float f; unsigned u; } u;
    u.u = ((unsigned)(unsigned short)s) << 16;
    return u.f;
}

__device__ inline float fast_sigmoid(float x) {
    return __builtin_amdgcn_rcpf(1.0f + __expf(-x));
}

__device__ inline float fast_tanh(float x) {
    float e = __expf(-2.0f * x);
    return 2.0f * __builtin_amdgcn_rcpf(1.0f + e) - 1.0f;
}

// Barrier that drains ONLY lgkmcnt (LDS) — global loads stay in flight across
// it. __syncthreads would drain vmcnt(0) and expose HBM latency every step.
__device__ inline void block_sync_lds() {
    asm volatile("s_waitcnt lgkmcnt(0)\n\ts_barrier" ::: "memory");
}

// One block per batch element; 512 threads = 8 waves; 1 block/CU.
// Wave w owns hidden cols [16w,16w+16) x 4 gate types -> i/f/g/o of a column
// land in one lane's accumulators -> in-register elementwise, c in registers.
// ONE lgkm-only barrier per step. x A-frags prefetched register-direct from
// global 2 steps before use (tw==13 -> tw==15). pre_x packed [t][col*4+e]
// (wave-local, conflict-free). No global stores inside the loop.
__global__ __launch_bounds__(512, 2) void tamlstm_kernel(
    const float* __restrict__ xd,    // [B,T,D]
    const float* __restrict__ xs,    // [B,L]
    const float* __restrict__ Wih,   // [4H,D]
    const float* __restrict__ Whh,   // [4H,H]
    const float* __restrict__ Wzh,   // [4H,L]
    const float* __restrict__ bias,  // [4H]
    const float* __restrict__ Wout,  // [1,H]
    const float* __restrict__ bout,  // [1]
    float* __restrict__ out)         // [B,T]
{
    const int b    = blockIdx.x;
    const int tid  = threadIdx.x;
    const int w    = tid >> 6;    // wave 0..7
    const int lane = tid & 63;
    const int l15  = lane & 15;
    const int q    = lane >> 4;   // quad 0..3

    __shared__ __align__(16) float pre_x[16][PXS];   // 33 KB, wave-local
    __shared__ __align__(16) short h_ring[32][H_];   // 8 KB bf16 h history
    __shared__ float out_lds[T_];                    // 2 KB output buffer

    {   // zero h_ring (slot 0 = h_{-1} = 0)
        int* hr = (int*)h_ring;  // 2048 ints
        #pragma unroll
        for (int i = 0; i < 4; ++i) hr[tid + 512 * i] = 0;
    }

    const int col = (w << 4) + l15;                 // hidden column 0..127

    // ---- B-fragments (bf16) in registers ----
    // B-frag element j = W[gate = col + 128e][k = 32s + 8q + j]
    short8 whh[4][4];  // [gate e][k-chunk s], K=128
    short8 wih[4][2];  // [e][s], K=64
    #pragma unroll
    for (int e = 0; e < 4; ++e) {
        const int g = col + (e << 7);
        const float* rh = Whh + g * H_;
        #pragma unroll
        for (int s = 0; s < 4; ++s) {
            const float* p = rh + s * 32 + q * 8;
            short8 v;
            #pragma unroll
            for (int j = 0; j < 8; ++j) v[j] = f2bf(p[j]);
            whh[e][s] = v;
        }
        const float* ri = Wih + g * D_;
        #pragma unroll
        for (int s = 0; s < 2; ++s) {
            const float* p = ri + s * 32 + q * 8;
            short8 v;
            #pragma unroll
            for (int j = 0; j < 8; ++j) v[j] = f2bf(p[j]);
            wih[e][s] = v;
        }
    }

    // ---- static part: bias + x_static @ Wzh^T (folded into pre_x at dump) ----
    float S[4];
    const float* xsb = xs + b * L_;
    #pragma unroll
    for (int e = 0; e < 4; ++e) {
        const int g = col + (e << 7);
        const float* wz = Wzh + g * L_;
        float a = bias[g];
        for (int l = 0; l < L_; ++l) a += xsb[l] * wz[l];
        S[e] = a;
    }
    const float wo0 = Wout[lane];
    const float wo1 = Wout[lane + 64];
    const float bo  = bout[0];

    const float* xb = xd + (size_t)b * T_ * D_;

    // ---- prologue: window-0 pre_x (each wave its own cols; M=16 timesteps) ----
    {
        const float* xr = xb + l15 * D_;            // timestep row l15
        float4 u0 = *(const float4*)(xr + q * 8);
        float4 u1 = *(const float4*)(xr + q * 8 + 4);
        float4 u2 = *(const float4*)(xr + 32 + q * 8);
        float4 u3 = *(const float4*)(xr + 32 + q * 8 + 4);
        short8 a0, a1;
        a0[0]=f2bf(u0.x); a0[1]=f2bf(u0.y); a0[2]=f2bf(u0.z); a0[3]=f2bf(u0.w);
        a0[4]=f2bf(u1.x); a0[5]=f2bf(u1.y); a0[6]=f2bf(u1.z); a0[7]=f2bf(u1.w);
        a1[0]=f2bf(u2.x); a1[1]=f2bf(u2.y); a1[2]=f2bf(u2.z); a1[3]=f2bf(u2.w);
        a1[4]=f2bf(u3.x); a1[5]=f2bf(u3.y); a1[6]=f2bf(u3.z); a1[7]=f2bf(u3.w);
        floatx4 aw[4];
        #pragma unroll
        for (int e = 0; e < 4; ++e) {
            aw[e] = __builtin_amdgcn_mfma_f32_16x16x32_bf16(a0, wih[e][0],
                        (floatx4){0.f, 0.f, 0.f, 0.f}, 0, 0, 0);
            aw[e] = __builtin_amdgcn_mfma_f32_16x16x32_bf16(a1, wih[e][1], aw[e], 0, 0, 0);
        }
        #pragma unroll
        for (int r = 0; r < 4; ++r) {
            floatx4 pk = {aw[0][r] + S[0], aw[1][r] + S[1],
                          aw[2][r] + S[2], aw[3][r] + S[3]};
            *(floatx4*)&pre_x[q * 4 + r][col << 2] = pk;
        }
    }

    float c = 0.0f;
    float4 xv0, xv1, xv2, xv3;     // in-flight x A-rows for next window

    __syncthreads();               // h_ring zero + (pre_x is wave-local)

    for (int t = 0; t < T_; ++t) {
        const int tw = t & 15;

        // ---- h + pre_x LDS reads first (independent, pipelined) ----
        const short8* hp = (const short8*)h_ring[t & 31];
        short8 af0 = hp[q];
        short8 af1 = hp[4 + q];
        short8 af2 = hp[8 + q];
        short8 af3 = hp[12 + q];
        floatx4 px = *(const floatx4*)&pre_x[tw][col << 2];

        // ---- recurrent MFMA: two 2-deep chains ----
        floatx4 accA[4], accB[4];
        #pragma unroll
        for (int e = 0; e < 4; ++e) {
            accA[e] = __builtin_amdgcn_mfma_f32_16x16x32_bf16(af0, whh[e][0],
                          (floatx4){0.f, 0.f, 0.f, 0.f}, 0, 0, 0);
            accB[e] = __builtin_amdgcn_mfma_f32_16x16x32_bf16(af2, whh[e][2],
                          (floatx4){0.f, 0.f, 0.f, 0.f}, 0, 0, 0);
        }
        #pragma unroll
        for (int e = 0; e < 4; ++e) {
            accA[e] = __builtin_amdgcn_mfma_f32_16x16x32_bf16(af1, whh[e][1], accA[e], 0, 0, 0);
            accB[e] = __builtin_amdgcn_mfma_f32_16x16x32_bf16(af3, whh[e][3], accB[e], 0, 0, 0);
        }

        // ---- prefetch next window's x (issued 2 steps before use; raw
        //      barriers don't drain vmcnt -> stays in flight) ----
        if (tw == 13 && t + 3 < T_) {
            const float* xr = xb + (size_t)(t + 3 + l15) * D_;  // t+3 = t0+16
            xv0 = *(const float4*)(xr + q * 8);
            xv1 = *(const float4*)(xr + q * 8 + 4);
            xv2 = *(const float4*)(xr + 32 + q * 8);
            xv3 = *(const float4*)(xr + 32 + q * 8 + 4);
        }

        // ---- deferred output dot for window W-1 (quiet step; 2 t's/wave) ----
        if (tw == 5 && t >= 16) {
            const int tp = (t & ~15) - 16 + (w << 1);
            const int s0 = (tp + 1) & 31;
            const int s1 = (tp + 2) & 31;
            float p0 = bf2f(h_ring[s0][lane]) * wo0 + bf2f(h_ring[s0][lane + 64]) * wo1;
            float p1 = bf2f(h_ring[s1][lane]) * wo0 + bf2f(h_ring[s1][lane + 64]) * wo1;
            #pragma unroll
            for (int d = 32; d >= 1; d >>= 1) {
                p0 += __shfl_xor(p0, d);
                p1 += __shfl_xor(p1, d);
            }
            if (lane == 0) {
                out_lds[tp]     = p0 + bo;
                out_lds[tp + 1] = p1 + bo;
            }
        }

        // ---- elementwise (S already folded into px) ----
        const float gi = accA[0].x + accB[0].x + px[0];
        const float gf = accA[1].x + accB[1].x + px[1];
        const float gg = accA[2].x + accB[2].x + px[2];
        const float go = accA[3].x + accB[3].x + px[3];
        const float is = fast_sigmoid(gi);
        const float fs = fast_sigmoid(gf);
        const float os = fast_sigmoid(go);
        const float tg = fast_tanh(gg);
        c = fs * c + is * tg;
        const float h = os * fast_tanh(c);

        if (lane < 16) h_ring[(t + 1) & 31][col] = f2bf(h);

        // ---- window step: convert prefetched x, x@Wih MFMAs, dump pre_x ----
        // (after this window's last pre_x read; pre_x is wave-local)
        if (tw == 15 && t + 1 < T_) {
            short8 a0, a1;
            a0[0]=f2bf(xv0.x); a0[1]=f2bf(xv0.y); a0[2]=f2bf(xv0.z); a0[3]=f2bf(xv0.w);
            a0[4]=f2bf(xv1.x); a0[5]=f2bf(xv1.y); a0[6]=f2bf(xv1.z); a0[7]=f2bf(xv1.w);
            a1[0]=f2bf(xv2.x); a1[1]=f2bf(xv2.y); a1[2]=f2bf(xv2.z); a1[3]=f2bf(xv2.w);
            a1[4]=f2bf(xv3.x); a1[5]=f2bf(xv3.y); a1[6]=f2bf(xv3.z); a1[7]=f2bf(xv3.w);
            floatx4 aw[4];
            #pragma unroll
            for (int e = 0; e < 4; ++e) {
                aw[e] = __builtin_amdgcn_mfma_f32_16x16x32_bf16(a0, wih[e][0],
                            (floatx4){0.f, 0.f, 0.f, 0.f}, 0, 0, 0);
                aw[e] = __builtin_amdgcn_mfma_f32_16x16x32_bf16(a1, wih[e][1], aw[e], 0, 0, 0);
            }
            #pragma unroll
            for (int r = 0; r < 4; ++r) {
                floatx4 pk = {aw[0][r] + S[0], aw[1][r] + S[1],
                              aw[2][r] + S[2], aw[3][r] + S[3]};
                *(floatx4*)&pre_x[q * 4 + r][col << 2] = pk;
            }
        }

        block_sync_lds();
    }

    // ---- epilogue: output dots for t' = 480..511 (4 per wave) ----
    #pragma unroll
    for (int i = 0; i < 4; ++i) {
        const int tp = T_ - 32 + (w << 2) + i;
        const int s0 = (tp + 1) & 31;
        float p0 = bf2f(h_ring[s0][lane]) * wo0 + bf2f(h_ring[s0][lane + 64]) * wo1;
        #pragma unroll
        for (int d = 32; d >= 1; d >>= 1) p0 += __shfl_xor(p0, d);
        if (lane == 0) out_lds[tp] = p0 + bo;
    }
    __syncthreads();
    out[b * T_ + tid] = out_lds[tid];
}

extern "C" void kernel_launch(void* const* d_in, const int* in_sizes, int n_in,
                              void* d_out, int out_size, void* d_ws, size_t ws_size,
                              hipStream_t stream) {
    const float* xd   = (const float*)d_in[0];
    const float* xs   = (const float*)d_in[1];
    const float* Wih  = (const float*)d_in[2];
    const float* Whh  = (const float*)d_in[3];
    const float* Wzh  = (const float*)d_in[4];
    const float* bias = (const float*)d_in[5];
    const float* Wout = (const float*)d_in[6];
    const float* bout = (const float*)d_in[7];
    float* o = (float*)d_out;
    hipLaunchKernelGGL(tamlstm_kernel, dim3(B_), dim3(512), 0, stream,
                       xd, xs, Wih, Whh, Wzh, bias, Wout, bout, o);
}